// Round 13
// baseline (780.680 us; speedup 1.0000x reference)
//
#include <hip/hip_runtime.h>

#define NN 64
#define PP 8732
#define CC 91
#define MM 20
#define RATIO 3
#define BPI 32                   // match chunks per image
#define CHUNK 273                // ceil(PP / BPI)
#define MBLK (NN * BPI)          // 2048 match-owning blocks
#define TILES (NN * PP / 64)     // 8732 ce tiles (64 rows each)

typedef unsigned long long u64;
typedef unsigned short u16;

// ---------------------------------------------------------------------------
// Init: zero mflag[NN] + tcnt[NN] + fincnt[1] (contiguous 129 ints).
// Dedicated kernel -> flags are fresh every replay (no cross-replay state).
// ---------------------------------------------------------------------------
__global__ void init_kernel(int* __restrict__ flags) {
  if (threadIdx.x < 2 * NN + 1) flags[threadIdx.x] = 0;
}

// ---------------------------------------------------------------------------
// Mega kernel: match (blocks 0..MBLK-1) -> flag release; all blocks: ce tile
// (sumexp first, then spin-acquire match flags); per-image finisher runs
// hard-negative mining; last finisher reduces -> out. All cross-block
// signaling: syncthreads-drain + threadfence + device atomics (r7/r8-proven).
// ---------------------------------------------------------------------------
__global__ __launch_bounds__(256, 4) void mega_kernel(
    const float* __restrict__ scores,        // N*P*C
    const float4* __restrict__ pred_locs4,   // N*P
    const float4* __restrict__ priors4,      // P
    const float4* __restrict__ boxes4,       // N*M
    const int* __restrict__ labels,          // N*M
    u16* __restrict__ minfo,                 // N*P packed (obj<<8|label)
    u64* __restrict__ combined_part,         // MBLK*MM
    float* __restrict__ ce_neg,              // N*P
    float4* __restrict__ partials,           // [TILES]
    float4* __restrict__ per_img,            // [NN]
    int* __restrict__ mflag,                 // [NN] match-done counters
    int* __restrict__ tcnt,                  // [NN] ce-tile counters
    int* __restrict__ fincnt,                // [1]
    float* __restrict__ out)
{
  __shared__ float pi_s[4][CHUNK];           // match: per-wave per-prior best
  __shared__ float pd_s[4][CHUNK];
  __shared__ short pm_s[4][CHUNK];
  __shared__ int lb_m[MM];
  __shared__ unsigned key_lo[2][MM];         // ce tables
  __shared__ int lbl_s[2][MM];
  __shared__ float4 box_s[2][MM];
  __shared__ float4 w4r[4];
  __shared__ int fin_s[2];
  __shared__ int4 cred[2][4];                // finisher
  __shared__ float wredf[4];
  __shared__ int wcnt[4];
  __shared__ float4 wacc[4];
  __shared__ int dd_s;

  const int bid = blockIdx.x, tid = threadIdx.x;
  const int wave = tid >> 6, lane = tid & 63;

  // ================= phase 1: match (blocks 0..MBLK-1) =================
  if (bid < MBLK) {
    const int n = bid >> 5, part = bid & 31;
    const int c0 = part * CHUNK;
    const int cend = (c0 + CHUNK < PP) ? c0 + CHUNK : PP;
    const int clen = cend - c0;

    if (tid < MM) lb_m[tid] = labels[n * MM + tid];

    float obx0[5], oby0[5], obx1[5], oby1[5], oba[5];
#pragma unroll
    for (int j = 0; j < 5; ++j) {
      float4 b = boxes4[n * MM + wave * 5 + j];
      obx0[j] = b.x; oby0[j] = b.y; obx1[j] = b.z; oby1[j] = b.w;
      oba[j] = (b.z - b.x) * (b.w - b.y);
    }
    float bi[5], bd[5]; int bpp[5];
#pragma unroll
    for (int j = 0; j < 5; ++j) { bi[j] = 0.0f; bd[j] = 1.0f; bpp[j] = 0; }

#pragma unroll
    for (int i = 0; i < 5; ++i) {
      int pc = lane + (i << 6);
      if (pc < clen) {
        int p = c0 + pc;
        float4 pr = priors4[p];
        float hw = pr.z * 0.5f, hh = pr.w * 0.5f;
        float px0 = pr.x - hw, py0 = pr.y - hh;
        float px1 = pr.x + hw, py1 = pr.y + hh;
        float pa = (px1 - px0) * (py1 - py0);   // ref rounding
        float pi = -1.0f, pd = 1.0f; int pm = 0;
#pragma unroll
        for (int j = 0; j < 5; ++j) {
          float iw = fminf(obx1[j], px1) - fmaxf(obx0[j], px0);
          float ih = fminf(oby1[j], py1) - fmaxf(oby0[j], py0);
          iw = fmaxf(iw, 0.0f); ih = fmaxf(ih, 0.0f);
          float inter = iw * ih;
          float den = (oba[j] + pa) - inter;
          bool cA = inter * pd > pi * den;          // first j wins ties
          pi = cA ? inter : pi; pd = cA ? den : pd;
          pm = cA ? (wave * 5 + j) : pm;
          bool cB = inter * bd[j] > bi[j] * den;    // lowest p wins ties
          bi[j] = cB ? inter : bi[j]; bd[j] = cB ? den : bd[j];
          bpp[j] = cB ? p : bpp[j];
        }
        pi_s[wave][pc] = pi; pd_s[wave][pc] = pd; pm_s[wave][pc] = (short)pm;
      }
    }

#pragma unroll
    for (int j = 0; j < 5; ++j) {
      float rr = bi[j] / bd[j];                   // IEEE quotient, >= 0
      u64 key = ((u64)__float_as_uint(rr) << 32) |
                (unsigned)(~(unsigned)bpp[j]);
#pragma unroll
      for (int d = 1; d < 64; d <<= 1) {
        u64 o = __shfl_xor(key, d);
        key = (o > key) ? o : key;
      }
      if (lane == 0) combined_part[bid * MM + wave * 5 + j] = key;
    }
    __syncthreads();

    for (int pc = tid; pc < clen; pc += 256) {
      float pi = pi_s[0][pc], pd = pd_s[0][pc]; int pm = pm_s[0][pc];
#pragma unroll
      for (int w = 1; w < 4; ++w) {
        float qi = pi_s[w][pc], qd = pd_s[w][pc];
        bool c = qi * pd > pi * qd;               // later m only if strictly >
        int qm = pm_s[w][pc];
        pi = c ? qi : pi; pd = c ? qd : pd; pm = c ? qm : pm;
      }
      float q = pi / pd;                          // IEEE quotient (ref)
      int lab8 = (q < 0.5f) ? 0 : lb_m[pm];       // labels 1..90, never 0
      minfo[(size_t)n * PP + c0 + pc] = (u16)((pm << 8) | lab8);
    }

    __syncthreads();            // drain all threads' stores (vmcnt 0)
    if (tid == 0) {
      __threadfence();          // agent release (L2 writeback)
      atomicAdd(&mflag[n], 1);
    }
  }

  // ================= phase 2: ce tile = bid =================
  const long base = (long)bid * 64;
  const int n0 = (int)(base / PP);
  const int rem0 = (int)(base - (long)n0 * PP);
  const int n1 = (n0 + 1 < NN) ? n0 + 1 : NN - 1;
  const int r = tid >> 2, l = tid & 3;
  const long row = base + r;

  // sumexp first: no match dependency -> hides the flag wait
  const float* rp = scores + (size_t)row * CC;
  float ss0 = 0.f, ss1 = 0.f, ss2 = 0.f, ss3 = 0.f;
#pragma unroll
  for (int j = 0; j < 23; ++j) {
    int c = l + 4 * j;
    if (c < CC) {
      float e = __expf(rp[c]);
      if ((j & 3) == 0) ss0 += e;
      else if ((j & 3) == 1) ss1 += e;
      else if ((j & 3) == 2) ss2 += e;
      else ss3 += e;
    }
  }
  float s = (ss0 + ss1) + (ss2 + ss3);
  s += __shfl_xor(s, 1);
  s += __shfl_xor(s, 2);

  // wait for this tile's images' match data
  if (tid == 0) {
    while (__hip_atomic_load(&mflag[n0], __ATOMIC_ACQUIRE,
                             __HIP_MEMORY_SCOPE_AGENT) < BPI)
      __builtin_amdgcn_s_sleep(4);
    while (__hip_atomic_load(&mflag[n1], __ATOMIC_ACQUIRE,
                             __HIP_MEMORY_SCOPE_AGENT) < BPI)
      __builtin_amdgcn_s_sleep(4);
    __threadfence();            // agent acquire (invalidate)
  }
  __syncthreads();

  // stage per-image tables
  if (tid < MM) {
    const u64* cp = combined_part + (size_t)n0 * BPI * MM;
    u64 best = cp[tid];
#pragma unroll
    for (int w = 1; w < BPI; ++w) {
      u64 o = cp[w * MM + tid]; best = (o > best) ? o : best;
    }
    key_lo[0][tid] = (unsigned)best;
    lbl_s[0][tid]  = labels[n0 * MM + tid];
    box_s[0][tid]  = boxes4[n0 * MM + tid];
  } else if (tid >= 64 && tid < 64 + MM) {
    int j = tid - 64;
    const u64* cp = combined_part + (size_t)n1 * BPI * MM;
    u64 best = cp[j];
#pragma unroll
    for (int w = 1; w < BPI; ++w) {
      u64 o = cp[w * MM + j]; best = (o > best) ? o : best;
    }
    key_lo[1][j] = (unsigned)best;
    lbl_s[1][j]  = labels[n1 * MM + j];
    box_s[1][j]  = boxes4[n1 * MM + j];
  }
  const int mi = minfo[row];    // after acquire
  __syncthreads();

  float cp_ = 0.0f, lp_ = 0.0f; int pos0 = 0, pos1 = 0;
  if (l == 0) {
    const int bn = (rem0 + r >= PP) ? 1 : 0;
    const int p = rem0 + r - bn * PP;
    int mm_ = -1;
    const unsigned want = ~(unsigned)p;
#pragma unroll
    for (int j = 0; j < MM; ++j) if (key_lo[bn][j] == want) mm_ = j; // last wins
    bool pos; int lab, sm;
    if (mm_ >= 0) { pos = true; sm = mm_; lab = lbl_s[bn][mm_]; }
    else { lab = mi & 0xff; pos = (lab != 0); sm = mi >> 8; }
    float ce = __logf(s) - rp[lab];
    if (pos) {
      cp_ = ce; ce_neg[row] = 0.0f;
      if (bn) pos1 = 1; else pos0 = 1;
      float4 bx = box_s[bn][sm], pr = priors4[p], pl = pred_locs4[row];
      float cx = (bx.x + bx.z) * 0.5f, cy = (bx.y + bx.w) * 0.5f;
      float w = bx.z - bx.x, h = bx.w - bx.y;
      float gx = (cx - pr.x) / (pr.z / 10.0f);
      float gy = (cy - pr.y) / (pr.w / 10.0f);
      float gz = __logf(w / pr.z) * 5.0f;
      float gw = __logf(h / pr.w) * 5.0f;
      float d, a;
      d = pl.x - gx; a = fabsf(d); lp_ += (a < 1.0f) ? 0.5f * d * d : a - 0.5f;
      d = pl.y - gy; a = fabsf(d); lp_ += (a < 1.0f) ? 0.5f * d * d : a - 0.5f;
      d = pl.z - gz; a = fabsf(d); lp_ += (a < 1.0f) ? 0.5f * d * d : a - 0.5f;
      d = pl.w - gw; a = fabsf(d); lp_ += (a < 1.0f) ? 0.5f * d * d : a - 0.5f;
    } else {
      ce_neg[row] = fmaxf(ce, 0.0f);   // >=0 keeps uint order == float order
    }
  }

#pragma unroll
  for (int d = 1; d < 64; d <<= 1) {
    cp_ += __shfl_xor(cp_, d); lp_ += __shfl_xor(lp_, d);
    pos0 += __shfl_xor(pos0, d); pos1 += __shfl_xor(pos1, d);
  }
  if (lane == 0) w4r[wave] = make_float4(cp_, lp_, (float)pos0, (float)pos1);
  __syncthreads();              // drains ce_neg stores too

  if (tid == 0) {
    float4 a0 = w4r[0], a1 = w4r[1], a2 = w4r[2], a3 = w4r[3];
    partials[bid] = make_float4(a0.x + a1.x + a2.x + a3.x,
                                a0.y + a1.y + a2.y + a3.y,
                                a0.z + a1.z + a2.z + a3.z,
                                a0.w + a1.w + a2.w + a3.w);
    __threadfence();            // release ce_neg + partials
    int f0 = -1, f1 = -1;
    {
      int st0 = (n0 * PP) / 64, en0 = ((n0 + 1) * PP - 1) / 64;
      if (atomicAdd(&tcnt[n0], 1) == en0 - st0) f0 = n0;
    }
    if (n1 != n0 && rem0 + 63 >= PP) {   // tile actually spans image n1
      int st1 = (n1 * PP) / 64, en1 = ((n1 + 1) * PP - 1) / 64;
      if (atomicAdd(&tcnt[n1], 1) == en1 - st1) f1 = n1;
    } else if (n1 != n0) {
      // still must count: n1's table was read but no rows -> do not count
    }
    fin_s[0] = f0; fin_s[1] = f1;
  }
  __syncthreads();

  // ================= phase 3: per-image finisher(s) =================
  for (int fi = 0; fi < 2; ++fi) {
    const int nf = fin_s[fi];
    if (nf < 0) continue;
    __threadfence();            // acquire other blocks' ce_neg/partials

    const int bstart = (nf * PP) / 64;
    const int bend = ((nf + 1) * PP - 1) / 64;          // inclusive
    const int ost = (nf * PP + 63) / 64;                // owned start
    const int oen = ((nf + 1) * PP + 63) / 64;          // owned end (excl)
    float kc = 0.0f, cpo = 0.0f, lpo = 0.0f;
    for (int b = bstart + tid; b <= bend; b += 256) {
      float4 pb = partials[b];
      int nb0 = (int)(((long)b * 64) / PP);
      if (nb0 == nf)     kc += pb.z;
      if (nb0 + 1 == nf) kc += pb.w;
      if (b >= ost && b < oen) { cpo += pb.x; lpo += pb.y; }
    }
#pragma unroll
    for (int d = 1; d < 64; d <<= 1) {
      kc += __shfl_xor(kc, d); cpo += __shfl_xor(cpo, d);
      lpo += __shfl_xor(lpo, d);
    }
    if (lane == 0) wacc[wave] = make_float4(kc, cpo, lpo, 0.f);
    __syncthreads();
    kc  = wacc[0].x + wacc[1].x + wacc[2].x + wacc[3].x;
    cpo = wacc[0].y + wacc[1].y + wacc[2].y + wacc[3].y;
    lpo = wacc[0].z + wacc[1].z + wacc[2].z + wacc[3].z;
    const float npn = kc;
    const int k = RATIO * (int)(kc + 0.5f);

    unsigned uv[35];
    const float* cn = ce_neg + (size_t)nf * PP;
#pragma unroll
    for (int i = 0; i < 35; ++i) {
      int p = tid + (i << 8);
      uv[i] = (p < PP) ? __float_as_uint(cn[p]) : 0u;
    }

    float hs = 0.0f;            // valid on tid 0
    if (k >= PP) {
      float sx = 0.0f;
#pragma unroll
      for (int i = 0; i < 35; ++i) sx += __uint_as_float(uv[i]);
#pragma unroll
      for (int d = 1; d < 64; d <<= 1) sx += __shfl_xor(sx, d);
      __syncthreads();
      if (lane == 0) wredf[wave] = sx;
      __syncthreads();
      hs = wredf[0] + wredf[1] + wredf[2] + wredf[3];
    } else if (k > 0) {
      unsigned lo = 0u, hi = 0x7f7fffffu;
      int it = 0;
      while (lo < hi) {
        unsigned span = hi - lo;
        unsigned q4 = span >> 2;
        unsigned m1, m2, m3;
        if (q4 == 0) { m1 = m2 = m3 = lo + ((span + 1) >> 1); }
        else { m1 = lo + q4; m2 = lo + 2 * q4; m3 = lo + 3 * q4; }
        int a1 = 0, a2 = 0, a3 = 0;
#pragma unroll
        for (int i = 0; i < 35; ++i) {
          unsigned v = uv[i];
          a1 += (v >= m1); a2 += (v >= m2); a3 += (v >= m3);
        }
#pragma unroll
        for (int d = 1; d < 64; d <<= 1) {
          a1 += __shfl_xor(a1, d); a2 += __shfl_xor(a2, d);
          a3 += __shfl_xor(a3, d);
        }
        const int buf = it & 1;
        if (lane == 0) cred[buf][wave] = make_int4(a1, a2, a3, 0);
        __syncthreads();
        int c1 = 0, c2 = 0, c3 = 0;
#pragma unroll
        for (int w = 0; w < 4; ++w) {
          int4 cc = cred[buf][w];
          c1 += cc.x; c2 += cc.y; c3 += cc.z;
        }
        if (c3 >= k) lo = m3;
        else if (c2 >= k) { lo = m2; hi = m3 - 1; }
        else if (c1 >= k) { lo = m1; hi = m2 - 1; }
        else hi = m1 - 1;
        ++it;
      }
      const float x = __uint_as_float(lo);
      float sx = 0.0f; int c = 0;
#pragma unroll
      for (int i = 0; i < 35; ++i) {
        unsigned v = uv[i];
        if (v > lo) { sx += __uint_as_float(v); ++c; }
      }
#pragma unroll
      for (int d = 1; d < 64; d <<= 1) {
        sx += __shfl_xor(sx, d); c += __shfl_xor(c, d);
      }
      __syncthreads();
      if (lane == 0) { wredf[wave] = sx; wcnt[wave] = c; }
      __syncthreads();
      hs = (wredf[0] + wredf[1] + wredf[2] + wredf[3]) +
           (float)(k - (wcnt[0] + wcnt[1] + wcnt[2] + wcnt[3])) * x;
    }

    if (tid == 0) {
      per_img[nf] = make_float4(cpo, lpo, npn, hs);
      __threadfence();
      dd_s = atomicAdd(fincnt, 1);
    }
    __syncthreads();
    if (dd_s == NN - 1) {
      __threadfence();
      if (tid < 64) {
        float4 v = per_img[tid];
        float a = v.x, b = v.y, c = v.z, d = v.w;
#pragma unroll
        for (int dd = 1; dd < 64; dd <<= 1) {
          a += __shfl_xor(a, dd); b += __shfl_xor(b, dd);
          c += __shfl_xor(c, dd); d += __shfl_xor(d, dd);
        }
        if (tid == 0) out[0] = (a + d) / c + b / (c * 4.0f);
      }
    }
    __syncthreads();
  }
}

// ---------------------------------------------------------------------------
extern "C" void kernel_launch(void* const* d_in, const int* in_sizes, int n_in,
                              void* d_out, int out_size, void* d_ws, size_t ws_size,
                              hipStream_t stream) {
  const float*  pred_locs   = (const float*)d_in[0];
  const float*  pred_scores = (const float*)d_in[1];
  const float*  boxes       = (const float*)d_in[2];
  const int*    labels      = (const int*)d_in[3];
  const float*  priors      = (const float*)d_in[4];
  float* out = (float*)d_out;

  // workspace layout (16B-aligned sections)
  float4* partials = (float4*)d_ws;                               // TILES
  float*  ce_neg = (float*)(partials + TILES);                    // N*P
  u64* combined_part = (u64*)(ce_neg + (size_t)NN * PP);          // MBLK*MM
  float4* per_img = (float4*)(combined_part + (size_t)MBLK * MM); // NN
  int* flags = (int*)(per_img + NN);          // mflag[NN]+tcnt[NN]+fincnt[1]
  u16* minfo = (u16*)(flags + 132);                               // N*P u16

  int* mflag  = flags;
  int* tcnt   = flags + NN;
  int* fincnt = flags + 2 * NN;

  init_kernel<<<1, 256, 0, stream>>>(flags);
  mega_kernel<<<TILES, 256, 0, stream>>>(pred_scores,
                                         (const float4*)pred_locs,
                                         (const float4*)priors,
                                         (const float4*)boxes, labels,
                                         minfo, combined_part, ce_neg,
                                         partials, per_img,
                                         mflag, tcnt, fincnt, out);
}

// Round 14
// 150.470 us; speedup vs baseline: 5.1883x; 5.1883x over previous
//
#include <hip/hip_runtime.h>

#define NN 64
#define PP 8732
#define CC 91
#define MM 20
#define RATIO 3
#define BPI 32                   // match chunks per image
#define CHUNK 273                // ceil(PP / BPI)
#define MBLK (NN * BPI)          // 2048 match-owning blocks
#define TILES (NN * PP / 64)     // 8732 ce tiles (64 rows each)

typedef unsigned long long u64;

// ---------------------------------------------------------------------------
// Init: zero mflag[NN] + finisher counter (NN+1 ints). Fresh every replay.
// ---------------------------------------------------------------------------
__global__ void init_kernel(int* __restrict__ flags) {
  if (threadIdx.x < NN + 1) flags[threadIdx.x] = 0;
}

// ---------------------------------------------------------------------------
// Mega kernel: match (blocks 0..MBLK-1) handed to ce via FENCE-FREE protocol:
//   producer: relaxed agent atomic stores (sc1 -> Infinity Cache) + one
//             RELEASE atomicAdd on mflag[n]  (2048 producer-side drains only)
//   consumer: relaxed atomic spin on mflag + relaxed agent atomic loads of
//             minfo/combined (sc1 reads from IF; NO L2 invalidate -> the
//             203 MB score stream keeps its L2 locality; r13's poison was
//             8732 consumer-side invalidates)
// ce outputs (ce_neg, partials) are plain stores; the graph edge to the
// hardneg kernel is an implicit agent release (r8-proven).
// ---------------------------------------------------------------------------
__global__ __launch_bounds__(256) void mega_kernel(
    const float* __restrict__ scores,        // N*P*C
    const float4* __restrict__ pred_locs4,   // N*P
    const float4* __restrict__ priors4,      // P
    const float4* __restrict__ boxes4,       // N*M
    const int* __restrict__ labels,          // N*M
    unsigned* __restrict__ minfo,            // N*P u32 (obj<<8 | label)
    u64* __restrict__ combined_part,         // MBLK*MM
    float* __restrict__ ce_neg,              // N*P
    float4* __restrict__ partials,           // [TILES]
    int* __restrict__ mflag)                 // [NN]
{
  __shared__ float pi_s[4][CHUNK];
  __shared__ float pd_s[4][CHUNK];
  __shared__ short pm_s[4][CHUNK];
  __shared__ int lb_m[MM];
  __shared__ unsigned key_lo[2][MM];
  __shared__ int lbl_s[2][MM];
  __shared__ float4 box_s[2][MM];
  __shared__ float4 w4r[4];

  const int bid = blockIdx.x, tid = threadIdx.x;
  const int wave = tid >> 6, lane = tid & 63;

  // ================= phase 1: match (blocks 0..MBLK-1) =================
  if (bid < MBLK) {
    const int n = bid >> 5, part = bid & 31;
    const int c0 = part * CHUNK;
    const int cend = (c0 + CHUNK < PP) ? c0 + CHUNK : PP;
    const int clen = cend - c0;

    if (tid < MM) lb_m[tid] = labels[n * MM + tid];

    float obx0[5], oby0[5], obx1[5], oby1[5], oba[5];
#pragma unroll
    for (int j = 0; j < 5; ++j) {
      float4 b = boxes4[n * MM + wave * 5 + j];
      obx0[j] = b.x; oby0[j] = b.y; obx1[j] = b.z; oby1[j] = b.w;
      oba[j] = (b.z - b.x) * (b.w - b.y);
    }
    float bi[5], bd[5]; int bpp[5];
#pragma unroll
    for (int j = 0; j < 5; ++j) { bi[j] = 0.0f; bd[j] = 1.0f; bpp[j] = 0; }

#pragma unroll
    for (int i = 0; i < 5; ++i) {
      int pc = lane + (i << 6);
      if (pc < clen) {
        int p = c0 + pc;
        float4 pr = priors4[p];
        float hw = pr.z * 0.5f, hh = pr.w * 0.5f;
        float px0 = pr.x - hw, py0 = pr.y - hh;
        float px1 = pr.x + hw, py1 = pr.y + hh;
        float pa = (px1 - px0) * (py1 - py0);   // ref rounding
        float pi = -1.0f, pd = 1.0f; int pm = 0;
#pragma unroll
        for (int j = 0; j < 5; ++j) {
          float iw = fminf(obx1[j], px1) - fmaxf(obx0[j], px0);
          float ih = fminf(oby1[j], py1) - fmaxf(oby0[j], py0);
          iw = fmaxf(iw, 0.0f); ih = fmaxf(ih, 0.0f);
          float inter = iw * ih;
          float den = (oba[j] + pa) - inter;
          bool cA = inter * pd > pi * den;          // first j wins ties
          pi = cA ? inter : pi; pd = cA ? den : pd;
          pm = cA ? (wave * 5 + j) : pm;
          bool cB = inter * bd[j] > bi[j] * den;    // lowest p wins ties
          bi[j] = cB ? inter : bi[j]; bd[j] = cB ? den : bd[j];
          bpp[j] = cB ? p : bpp[j];
        }
        pi_s[wave][pc] = pi; pd_s[wave][pc] = pd; pm_s[wave][pc] = (short)pm;
      }
    }

#pragma unroll
    for (int j = 0; j < 5; ++j) {
      float rr = bi[j] / bd[j];                   // IEEE quotient, >= 0
      u64 key = ((u64)__float_as_uint(rr) << 32) |
                (unsigned)(~(unsigned)bpp[j]);
#pragma unroll
      for (int d = 1; d < 64; d <<= 1) {
        u64 o = __shfl_xor(key, d);
        key = (o > key) ? o : key;
      }
      if (lane == 0)
        __hip_atomic_store(&combined_part[bid * MM + wave * 5 + j], key,
                           __ATOMIC_RELAXED, __HIP_MEMORY_SCOPE_AGENT);
    }
    __syncthreads();

    for (int pc = tid; pc < clen; pc += 256) {
      float pi = pi_s[0][pc], pd = pd_s[0][pc]; int pm = pm_s[0][pc];
#pragma unroll
      for (int w = 1; w < 4; ++w) {
        float qi = pi_s[w][pc], qd = pd_s[w][pc];
        bool c = qi * pd > pi * qd;               // later m only if strictly >
        int qm = pm_s[w][pc];
        pi = c ? qi : pi; pd = c ? qd : pd; pm = c ? qm : pm;
      }
      float q = pi / pd;                          // IEEE quotient (ref)
      int lab8 = (q < 0.5f) ? 0 : lb_m[pm];       // labels 1..90, never 0
      __hip_atomic_store(&minfo[(size_t)n * PP + c0 + pc],
                         (unsigned)((pm << 8) | lab8),
                         __ATOMIC_RELAXED, __HIP_MEMORY_SCOPE_AGENT);
    }
    __syncthreads();
    if (tid == 0)
      __hip_atomic_fetch_add(&mflag[n], 1, __ATOMIC_RELEASE,
                             __HIP_MEMORY_SCOPE_AGENT);   // drains stores
  }

  // ================= phase 2: ce tile = bid (64 rows) =================
  const long base = (long)bid * 64;
  const int n0 = (int)(base / PP);
  const int rem0 = (int)(base - (long)n0 * PP);
  const bool spans = (rem0 + 63 >= PP) && (n0 + 1 < NN);
  const int n1 = spans ? n0 + 1 : n0;
  const int r = tid >> 2, l = tid & 3;
  const long row = base + r;

  // sumexp first: no match dependency -> hides the wait
  const float* rp = scores + (size_t)row * CC;
  float ss0 = 0.f, ss1 = 0.f, ss2 = 0.f, ss3 = 0.f;
#pragma unroll
  for (int j = 0; j < 23; ++j) {
    int c = l + 4 * j;
    if (c < CC) {
      float e = __expf(rp[c]);
      if ((j & 3) == 0) ss0 += e;
      else if ((j & 3) == 1) ss1 += e;
      else if ((j & 3) == 2) ss2 += e;
      else ss3 += e;
    }
  }
  float s = (ss0 + ss1) + (ss2 + ss3);
  s += __shfl_xor(s, 1);
  s += __shfl_xor(s, 2);

  // fence-free wait (relaxed loads; NO invalidate)
  if (tid == 0) {
    while (__hip_atomic_load(&mflag[n0], __ATOMIC_RELAXED,
                             __HIP_MEMORY_SCOPE_AGENT) < BPI)
      __builtin_amdgcn_s_sleep(2);
    if (spans)
      while (__hip_atomic_load(&mflag[n1], __ATOMIC_RELAXED,
                               __HIP_MEMORY_SCOPE_AGENT) < BPI)
        __builtin_amdgcn_s_sleep(2);
  }
  __syncthreads();                      // also a compiler barrier

  // stage tables via relaxed agent atomic loads (sc1, from IF)
  if (tid < MM) {
    const u64* cp = combined_part + (size_t)n0 * BPI * MM;
    u64 best = 0;
#pragma unroll
    for (int w = 0; w < BPI; ++w) {
      u64 o = __hip_atomic_load(&cp[w * MM + tid], __ATOMIC_RELAXED,
                                __HIP_MEMORY_SCOPE_AGENT);
      best = (o > best) ? o : best;
    }
    key_lo[0][tid] = (unsigned)best;
    lbl_s[0][tid]  = labels[n0 * MM + tid];
    box_s[0][tid]  = boxes4[n0 * MM + tid];
  } else if (tid >= 64 && tid < 64 + MM) {
    int j = tid - 64;
    const u64* cp = combined_part + (size_t)n1 * BPI * MM;
    u64 best = 0;
#pragma unroll
    for (int w = 0; w < BPI; ++w) {
      u64 o = __hip_atomic_load(&cp[w * MM + j], __ATOMIC_RELAXED,
                                __HIP_MEMORY_SCOPE_AGENT);
      best = (o > best) ? o : best;
    }
    key_lo[1][j] = (unsigned)best;
    lbl_s[1][j]  = labels[n1 * MM + j];
    box_s[1][j]  = boxes4[n1 * MM + j];
  }
  const unsigned mi = __hip_atomic_load(&minfo[row], __ATOMIC_RELAXED,
                                        __HIP_MEMORY_SCOPE_AGENT);
  __syncthreads();

  float cp_ = 0.0f, lp_ = 0.0f; int pos0 = 0, pos1 = 0;
  if (l == 0) {
    const int bn = (rem0 + r >= PP) ? 1 : 0;
    const int p = rem0 + r - bn * PP;
    int mm_ = -1;
    const unsigned want = ~(unsigned)p;
#pragma unroll
    for (int j = 0; j < MM; ++j) if (key_lo[bn][j] == want) mm_ = j; // last wins
    bool pos; int lab, sm;
    if (mm_ >= 0) { pos = true; sm = mm_; lab = lbl_s[bn][mm_]; }
    else { lab = (int)(mi & 0xffu); pos = (lab != 0); sm = (int)(mi >> 8); }
    float ce = __logf(s) - rp[lab];
    if (pos) {
      cp_ = ce; ce_neg[row] = 0.0f;
      if (bn) pos1 = 1; else pos0 = 1;
      float4 bx = box_s[bn][sm], pr = priors4[p], pl = pred_locs4[row];
      float cx = (bx.x + bx.z) * 0.5f, cy = (bx.y + bx.w) * 0.5f;
      float w = bx.z - bx.x, h = bx.w - bx.y;
      float gx = (cx - pr.x) / (pr.z / 10.0f);
      float gy = (cy - pr.y) / (pr.w / 10.0f);
      float gz = __logf(w / pr.z) * 5.0f;
      float gw = __logf(h / pr.w) * 5.0f;
      float d, a;
      d = pl.x - gx; a = fabsf(d); lp_ += (a < 1.0f) ? 0.5f * d * d : a - 0.5f;
      d = pl.y - gy; a = fabsf(d); lp_ += (a < 1.0f) ? 0.5f * d * d : a - 0.5f;
      d = pl.z - gz; a = fabsf(d); lp_ += (a < 1.0f) ? 0.5f * d * d : a - 0.5f;
      d = pl.w - gw; a = fabsf(d); lp_ += (a < 1.0f) ? 0.5f * d * d : a - 0.5f;
    } else {
      ce_neg[row] = fmaxf(ce, 0.0f);   // >=0 keeps uint order == float order
    }
  }

#pragma unroll
  for (int d = 1; d < 64; d <<= 1) {
    cp_ += __shfl_xor(cp_, d); lp_ += __shfl_xor(lp_, d);
    pos0 += __shfl_xor(pos0, d); pos1 += __shfl_xor(pos1, d);
  }
  if (lane == 0) w4r[wave] = make_float4(cp_, lp_, (float)pos0, (float)pos1);
  __syncthreads();
  if (tid == 0) {
    float4 a0 = w4r[0], a1 = w4r[1], a2 = w4r[2], a3 = w4r[3];
    partials[bid] = make_float4(a0.x + a1.x + a2.x + a3.x,
                                a0.y + a1.y + a2.y + a3.y,
                                a0.z + a1.z + a2.z + a3.z,
                                a0.w + a1.w + a2.w + a3.w);
  }
}

// ---------------------------------------------------------------------------
// Kernel C: hard-negative mining (4-ary bisection) + fused final.
// 64-row tile indexing. Graph edge from mega = implicit agent release.
// ---------------------------------------------------------------------------
__global__ __launch_bounds__(256) void hardneg_kernel(
    const float* __restrict__ ce_neg, const float4* __restrict__ partials,
    float4* __restrict__ per_img, int* __restrict__ counter,
    float* __restrict__ out)
{
  __shared__ int4 cred[2][4];
  __shared__ float wredf[4];
  __shared__ int wcnt[4];
  __shared__ float4 wacc[4];
  __shared__ int last_s;
  const int n = blockIdx.x, tid = threadIdx.x;

  unsigned uv[35];
#pragma unroll
  for (int i = 0; i < 35; ++i) {
    int p = tid + (i << 8);
    uv[i] = (p < PP) ? __float_as_uint(ce_neg[(size_t)n * PP + p]) : 0u;
  }

  float kc = 0.0f, cpo = 0.0f, lpo = 0.0f;
  {
    const int bstart = (n * PP) / 64;
    const int bend = ((n + 1) * PP - 1) / 64;            // inclusive
    const int ost = (n * PP + 63) / 64;                  // owned start
    const int oen = ((n + 1) * PP + 63) / 64;            // owned end (excl)
    for (int b = bstart + tid; b <= bend; b += 256) {
      float4 pb = partials[b];
      int nb0 = (int)(((long)b * 64) / PP);
      if (nb0 == n)     kc += pb.z;
      if (nb0 + 1 == n) kc += pb.w;
      if (b >= ost && b < oen) { cpo += pb.x; lpo += pb.y; }
    }
#pragma unroll
    for (int d = 1; d < 64; d <<= 1) {
      kc += __shfl_xor(kc, d); cpo += __shfl_xor(cpo, d);
      lpo += __shfl_xor(lpo, d);
    }
    if ((tid & 63) == 0) wacc[tid >> 6] = make_float4(kc, cpo, lpo, 0.f);
    __syncthreads();
    kc  = wacc[0].x + wacc[1].x + wacc[2].x + wacc[3].x;
    cpo = wacc[0].y + wacc[1].y + wacc[2].y + wacc[3].y;
    lpo = wacc[0].z + wacc[1].z + wacc[2].z + wacc[3].z;
  }
  const float npn = kc;
  const int k = RATIO * (int)(kc + 0.5f);

  float hs = 0.0f;
  if (k >= PP) {
    float s = 0.0f;
#pragma unroll
    for (int i = 0; i < 35; ++i) s += __uint_as_float(uv[i]);
#pragma unroll
    for (int d = 1; d < 64; d <<= 1) s += __shfl_xor(s, d);
    __syncthreads();
    if ((tid & 63) == 0) wredf[tid >> 6] = s;
    __syncthreads();
    hs = wredf[0] + wredf[1] + wredf[2] + wredf[3];
  } else if (k > 0) {
    unsigned lo = 0u, hi = 0x7f7fffffu;
    int it = 0;
    while (lo < hi) {
      unsigned span = hi - lo;
      unsigned q4 = span >> 2;
      unsigned m1, m2, m3;
      if (q4 == 0) { m1 = m2 = m3 = lo + ((span + 1) >> 1); }
      else { m1 = lo + q4; m2 = lo + 2 * q4; m3 = lo + 3 * q4; }
      int a1 = 0, a2 = 0, a3 = 0;
#pragma unroll
      for (int i = 0; i < 35; ++i) {
        unsigned v = uv[i];
        a1 += (v >= m1); a2 += (v >= m2); a3 += (v >= m3);
      }
#pragma unroll
      for (int d = 1; d < 64; d <<= 1) {
        a1 += __shfl_xor(a1, d); a2 += __shfl_xor(a2, d);
        a3 += __shfl_xor(a3, d);
      }
      const int buf = it & 1;
      if ((tid & 63) == 0) cred[buf][tid >> 6] = make_int4(a1, a2, a3, 0);
      __syncthreads();
      int c1 = 0, c2 = 0, c3 = 0;
#pragma unroll
      for (int w = 0; w < 4; ++w) {
        int4 cc = cred[buf][w];
        c1 += cc.x; c2 += cc.y; c3 += cc.z;
      }
      if (c3 >= k) lo = m3;
      else if (c2 >= k) { lo = m2; hi = m3 - 1; }
      else if (c1 >= k) { lo = m1; hi = m2 - 1; }
      else hi = m1 - 1;
      ++it;
    }
    const float x = __uint_as_float(lo);
    float s = 0.0f; int c = 0;
#pragma unroll
    for (int i = 0; i < 35; ++i) {
      unsigned v = uv[i];
      if (v > lo) { s += __uint_as_float(v); ++c; }
    }
#pragma unroll
    for (int d = 1; d < 64; d <<= 1) { s += __shfl_xor(s, d); c += __shfl_xor(c, d); }
    __syncthreads();
    if ((tid & 63) == 0) { wredf[tid >> 6] = s; wcnt[tid >> 6] = c; }
    __syncthreads();
    hs = (wredf[0] + wredf[1] + wredf[2] + wredf[3]) +
         (float)(k - (wcnt[0] + wcnt[1] + wcnt[2] + wcnt[3])) * x;
  }

  if (tid == 0) {
    per_img[n] = make_float4(cpo, lpo, npn, hs);
    __threadfence();
    last_s = atomicAdd(counter, 1);
  }
  __syncthreads();
  if (last_s == NN - 1) {
    __threadfence();
    if (tid < 64) {
      float4 v = per_img[tid];
      float a = v.x, b = v.y, c = v.z, d = v.w;
#pragma unroll
      for (int dd = 1; dd < 64; dd <<= 1) {
        a += __shfl_xor(a, dd); b += __shfl_xor(b, dd);
        c += __shfl_xor(c, dd); d += __shfl_xor(d, dd);
      }
      if (tid == 0) out[0] = (a + d) / c + b / (c * 4.0f);
    }
  }
}

// ---------------------------------------------------------------------------
extern "C" void kernel_launch(void* const* d_in, const int* in_sizes, int n_in,
                              void* d_out, int out_size, void* d_ws, size_t ws_size,
                              hipStream_t stream) {
  const float*  pred_locs   = (const float*)d_in[0];
  const float*  pred_scores = (const float*)d_in[1];
  const float*  boxes       = (const float*)d_in[2];
  const int*    labels      = (const int*)d_in[3];
  const float*  priors      = (const float*)d_in[4];
  float* out = (float*)d_out;

  // workspace layout (16B-aligned sections)
  float4* partials = (float4*)d_ws;                               // TILES
  float*  ce_neg = (float*)(partials + TILES);                    // N*P
  u64* combined_part = (u64*)(ce_neg + (size_t)NN * PP);          // MBLK*MM
  float4* per_img = (float4*)(combined_part + (size_t)MBLK * MM); // NN
  unsigned* minfo = (unsigned*)(per_img + NN);                    // N*P u32
  int* flags = (int*)(minfo + (size_t)NN * PP);   // mflag[NN] + counter[1]

  int* mflag   = flags;
  int* counter = flags + NN;

  init_kernel<<<1, 128, 0, stream>>>(flags);
  mega_kernel<<<TILES, 256, 0, stream>>>(pred_scores,
                                         (const float4*)pred_locs,
                                         (const float4*)priors,
                                         (const float4*)boxes, labels,
                                         minfo, combined_part, ce_neg,
                                         partials, mflag);
  hardneg_kernel<<<NN, 256, 0, stream>>>(ce_neg, partials, per_img,
                                         counter, out);
}

// Round 15
// 82.775 us; speedup vs baseline: 9.4313x; 1.8178x over previous
//
#include <hip/hip_runtime.h>

#define NN 64
#define PP 8732
#define CC 91
#define MM 20
#define RATIO 3
#define BPI 32                   // match chunks per image
#define CHUNK 273                // ceil(PP / BPI)
#define ROWS 128                 // ce rows per block
#define BTHR 512                 // ce threads per block
#define TILES2 ((NN * PP) / ROWS)   // 4366 ce tiles

typedef unsigned long long u64;

// ---------------------------------------------------------------------------
// Kernel 1: match_lite. 2048 blocks x 256 thr; wave w owns objects [5w,5w+5).
// ONLY per-object best-prior tracking (the global part); the per-prior argmax
// is recomputed locally by ce. No big LDS, no minfo -> high occupancy.
// key = float_bits(iou)<<32 | ~prior  (exact ref rounding via one div/object).
// ---------------------------------------------------------------------------
__global__ __launch_bounds__(256) void match_lite(
    const float4* __restrict__ boxes4,   // N*M (xyxy)
    const float4* __restrict__ priors4,  // P (cxcywh)
    u64* __restrict__ combined_part,     // (NN*BPI)*MM, block-exclusive
    int* __restrict__ counter)           // [1] -> zeroed here (hn finisher)
{
  const int blk = blockIdx.x, tid = threadIdx.x;
  const int wave = tid >> 6, lane = tid & 63;
  const int n = blk >> 5, part = blk & 31;
  const int c0 = part * CHUNK;
  const int cend = (c0 + CHUNK < PP) ? c0 + CHUNK : PP;

  if (blk == 0 && tid == 0) counter[0] = 0;

  float obx0[5], oby0[5], obx1[5], oby1[5], oba[5];
#pragma unroll
  for (int j = 0; j < 5; ++j) {
    float4 b = boxes4[n * MM + wave * 5 + j];
    obx0[j] = b.x; oby0[j] = b.y; obx1[j] = b.z; oby1[j] = b.w;
    oba[j] = (b.z - b.x) * (b.w - b.y);
  }
  float bi[5], bd[5]; int bpp[5];
#pragma unroll
  for (int j = 0; j < 5; ++j) { bi[j] = 0.0f; bd[j] = 1.0f; bpp[j] = 0; }

#pragma unroll
  for (int i = 0; i < 5; ++i) {
    int p = c0 + lane + (i << 6);
    if (p < cend) {
      float4 pr = priors4[p];
      float hw = pr.z * 0.5f, hh = pr.w * 0.5f;
      float px0 = pr.x - hw, py0 = pr.y - hh;
      float px1 = pr.x + hw, py1 = pr.y + hh;
      float pa = (px1 - px0) * (py1 - py0);     // ref rounding
#pragma unroll
      for (int j = 0; j < 5; ++j) {
        float iw = fminf(obx1[j], px1) - fmaxf(obx0[j], px0);
        float ih = fminf(oby1[j], py1) - fmaxf(oby0[j], py0);
        iw = fmaxf(iw, 0.0f); ih = fmaxf(ih, 0.0f);
        float inter = iw * ih;
        float den = (oba[j] + pa) - inter;
        bool c = inter * bd[j] > bi[j] * den;   // lowest p wins ties
        bi[j] = c ? inter : bi[j]; bd[j] = c ? den : bd[j];
        bpp[j] = c ? p : bpp[j];
      }
    }
  }

#pragma unroll
  for (int j = 0; j < 5; ++j) {
    float r = bi[j] / bd[j];                    // IEEE quotient (ref)
    u64 key = ((u64)__float_as_uint(r) << 32) | (unsigned)(~(unsigned)bpp[j]);
#pragma unroll
    for (int d = 1; d < 64; d <<= 1) {
      u64 o = __shfl_xor(key, d);
      key = (o > key) ? o : key;
    }
    if (lane == 0) combined_part[blk * MM + wave * 5 + j] = key;
  }
}

// ---------------------------------------------------------------------------
// Kernel 2: reduce combined_part (32 parts) -> combined (1 table/image).
// 64 blocks; tid<160: object j=tid>>3, slice w=tid&7 (4 parts each) + 8-lane
// shfl tree. Kernel boundary gives ce a coherent view (no fences needed).
// ---------------------------------------------------------------------------
__global__ __launch_bounds__(192) void reduce_kernel(
    const u64* __restrict__ combined_part, u64* __restrict__ combined)
{
  const int n = blockIdx.x, tid = threadIdx.x;
  if (tid < 160) {
    const int j = tid >> 3, w = tid & 7;
    const u64* cp = combined_part + (size_t)n * BPI * MM;
    u64 best = 0;
#pragma unroll
    for (int k = 0; k < 4; ++k) {
      u64 o = cp[(w * 4 + k) * MM + j];
      best = (o > best) ? o : best;
    }
    u64 o;
    o = __shfl_down(best, 4, 8); best = (o > best) ? o : best;
    o = __shfl_down(best, 2, 8); best = (o > best) ? o : best;
    o = __shfl_down(best, 1, 8); best = (o > best) ? o : best;
    if (w == 0) combined[n * MM + j] = best;
  }
}

// ---------------------------------------------------------------------------
// Kernel 3: CE + INLINE per-row match + smooth-L1 loc loss.
// 128 rows/block, 512 thr, direct-global scores (r8-proven). Each row's 4
// lanes recompute its prior-vs-20-objects argmax (lane l owns m=l,l+4,..;
// in-lane strict > = first-max; cross-lane tie -> lower m). Override via the
// 20-entry combined table (normal loads; coherent across kernel boundary).
// partials[b] = (conf_pos_sum, loc_sum, n_pos img n0, n_pos img n0+1).
// ---------------------------------------------------------------------------
__global__ __launch_bounds__(BTHR) void ce_kernel(
    const float* __restrict__ scores,        // N*P*C
    const float4* __restrict__ pred_locs4,   // N*P
    const float4* __restrict__ priors4,      // P
    const float4* __restrict__ boxes4,       // N*M
    const int* __restrict__ labels,          // N*M
    const u64* __restrict__ combined,        // NN*MM
    float* __restrict__ ce_neg,              // N*P (0 where positive)
    float4* __restrict__ partials)           // [TILES2]
{
  __shared__ unsigned key_lo[2][MM];
  __shared__ int lbl_s[2][MM];
  __shared__ float4 box_s[2][MM];
  __shared__ float4 w8[8];
  const int tid = threadIdx.x;
  const long base = (long)blockIdx.x * ROWS;
  const int n0 = (int)(base / PP);
  const int rem0 = (int)(base - (long)n0 * PP);
  const int r = tid >> 2, l = tid & 3;
  const long row = base + r;

  // stage per-image tables (block spans at most 2 images)
  if (tid < MM) {
    key_lo[0][tid] = (unsigned)combined[n0 * MM + tid];
    lbl_s[0][tid]  = labels[n0 * MM + tid];
    box_s[0][tid]  = boxes4[n0 * MM + tid];
  } else if (tid >= 64 && tid < 64 + MM) {
    int j = tid - 64, nn = (n0 + 1 < NN) ? n0 + 1 : NN - 1;
    key_lo[1][j] = (unsigned)combined[nn * MM + j];
    lbl_s[1][j]  = labels[nn * MM + j];
    box_s[1][j]  = boxes4[nn * MM + j];
  }

  // direct-from-global sumexp (independent of tables -> hides staging)
  const float* rp = scores + (size_t)row * CC;
  float ss0 = 0.f, ss1 = 0.f, ss2 = 0.f, ss3 = 0.f;
#pragma unroll
  for (int j = 0; j < 23; ++j) {
    int c = l + 4 * j;
    if (c < CC) {
      float e = __expf(rp[c]);
      if ((j & 3) == 0) ss0 += e;
      else if ((j & 3) == 1) ss1 += e;
      else if ((j & 3) == 2) ss2 += e;
      else ss3 += e;
    }
  }
  float s = (ss0 + ss1) + (ss2 + ss3);
  s += __shfl_xor(s, 1);
  s += __shfl_xor(s, 2);

  __syncthreads();   // tables ready

  // inline per-row match: this row's prior vs its image's 20 objects
  const int bn = (rem0 + r >= PP) ? 1 : 0;
  const int p = rem0 + r - bn * PP;
  const float4 pr4 = priors4[p];
  float bi, bd; int bm;
  {
    float hw = pr4.z * 0.5f, hh = pr4.w * 0.5f;
    float px0 = pr4.x - hw, py0 = pr4.y - hh;
    float px1 = pr4.x + hw, py1 = pr4.y + hh;
    float pa = (px1 - px0) * (py1 - py0);       // ref rounding
    bi = -1.0f; bd = 1.0f; bm = l;              // lane l owns m = l, l+4, ...
#pragma unroll
    for (int j5 = 0; j5 < 5; ++j5) {
      int m = l + 4 * j5;
      float4 bx = box_s[bn][m];
      float iw = fminf(bx.z, px1) - fmaxf(bx.x, px0);
      float ih = fminf(bx.w, py1) - fmaxf(bx.y, py0);
      iw = fmaxf(iw, 0.0f); ih = fmaxf(ih, 0.0f);
      float inter = iw * ih;
      float ba = (bx.z - bx.x) * (bx.w - bx.y);
      float den = (ba + pa) - inter;
      bool c = inter * bd > bi * den;           // in-lane: first m wins ties
      bi = c ? inter : bi; bd = c ? den : bd; bm = c ? m : bm;
    }
    // cross-lane combine within the row's 4 lanes: tie -> lower m
#pragma unroll
    for (int d = 1; d < 4; d <<= 1) {
      float oi = __shfl_xor(bi, d), od = __shfl_xor(bd, d);
      int om = __shfl_xor(bm, d);
      float a = oi * bd, b2 = bi * od;
      bool take = (a > b2) || (a == b2 && om < bm);
      bi = take ? oi : bi; bd = take ? od : bd; bm = take ? om : bm;
    }
  }

  float cp_ = 0.0f, lp_ = 0.0f; int pos0 = 0, pos1 = 0;
  if (l == 0) {
    // override scan: is this prior some object's global best? (last j wins)
    int mm_ = -1;
    const unsigned want = ~(unsigned)p;
#pragma unroll
    for (int j = 0; j < MM; ++j) if (key_lo[bn][j] == want) mm_ = j;
    bool pos; int lab, sm;
    if (mm_ >= 0) { pos = true; sm = mm_; lab = lbl_s[bn][mm_]; }
    else {
      float q = bi / bd;                        // IEEE quotient (ref)
      pos = !(q < 0.5f);
      sm = bm; lab = pos ? lbl_s[bn][bm] : 0;
    }
    float ce = __logf(s) - rp[lab];
    if (pos) {
      cp_ = ce; ce_neg[row] = 0.0f;
      if (bn) pos1 = 1; else pos0 = 1;
      float4 bx = box_s[bn][sm], pl = pred_locs4[row];
      float cx = (bx.x + bx.z) * 0.5f, cy = (bx.y + bx.w) * 0.5f;
      float w = bx.z - bx.x, h = bx.w - bx.y;
      float gx = (cx - pr4.x) / (pr4.z / 10.0f);
      float gy = (cy - pr4.y) / (pr4.w / 10.0f);
      float gz = __logf(w / pr4.z) * 5.0f;
      float gw = __logf(h / pr4.w) * 5.0f;
      float d, a;
      d = pl.x - gx; a = fabsf(d); lp_ += (a < 1.0f) ? 0.5f * d * d : a - 0.5f;
      d = pl.y - gy; a = fabsf(d); lp_ += (a < 1.0f) ? 0.5f * d * d : a - 0.5f;
      d = pl.z - gz; a = fabsf(d); lp_ += (a < 1.0f) ? 0.5f * d * d : a - 0.5f;
      d = pl.w - gw; a = fabsf(d); lp_ += (a < 1.0f) ? 0.5f * d * d : a - 0.5f;
    } else {
      ce_neg[row] = fmaxf(ce, 0.0f);   // >=0 keeps uint order == float order
    }
  }

#pragma unroll
  for (int d = 1; d < 64; d <<= 1) {
    cp_ += __shfl_xor(cp_, d); lp_ += __shfl_xor(lp_, d);
    pos0 += __shfl_xor(pos0, d); pos1 += __shfl_xor(pos1, d);
  }
  if ((tid & 63) == 0)
    w8[tid >> 6] = make_float4(cp_, lp_, (float)pos0, (float)pos1);
  __syncthreads();
  if (tid == 0) {
    float sx = 0.f, sy = 0.f, sz = 0.f, sw = 0.f;
#pragma unroll
    for (int w = 0; w < 8; ++w) { sx += w8[w].x; sy += w8[w].y; sz += w8[w].z; sw += w8[w].w; }
    partials[blockIdx.x] = make_float4(sx, sy, sz, sw);
  }
}

// ---------------------------------------------------------------------------
// Kernel 4: hard-negative mining (4-ary bisection, uint4 loads) + fused final.
// ---------------------------------------------------------------------------
__global__ __launch_bounds__(256) void hardneg_kernel(
    const float* __restrict__ ce_neg, const float4* __restrict__ partials,
    float4* __restrict__ per_img, int* __restrict__ counter,
    float* __restrict__ out)
{
  __shared__ int4 cred[2][4];
  __shared__ float wredf[4];
  __shared__ int wcnt[4];
  __shared__ float4 wacc[4];
  __shared__ int last_s;
  const int n = blockIdx.x, tid = threadIdx.x;

  // PP = 8732 = 4*2183 exactly: image slice is uint4-aligned and exact
  uint4 uv[9];
  {
    const uint4* cn4 = (const uint4*)(ce_neg + (size_t)n * PP);
#pragma unroll
    for (int i = 0; i < 9; ++i) {
      int f = tid + (i << 8);
      uv[i] = (f < 2183) ? cn4[f] : make_uint4(0u, 0u, 0u, 0u);
    }
  }

  float kc = 0.0f, cpo = 0.0f, lpo = 0.0f;
  {
    const int bstart = (n * PP) / ROWS;
    const int bend = ((n + 1) * PP - 1) / ROWS;
    const int ost = (n * PP + ROWS - 1) / ROWS;
    const int oen = ((n + 1) * PP + ROWS - 1) / ROWS;
    for (int b = bstart + tid; b <= bend; b += 256) {
      float4 pb = partials[b];
      int nb0 = (b * ROWS) / PP;
      if (nb0 == n)     kc += pb.z;
      if (nb0 + 1 == n) kc += pb.w;
      if (b >= ost && b < oen) { cpo += pb.x; lpo += pb.y; }
    }
#pragma unroll
    for (int d = 1; d < 64; d <<= 1) {
      kc += __shfl_xor(kc, d); cpo += __shfl_xor(cpo, d);
      lpo += __shfl_xor(lpo, d);
    }
    if ((tid & 63) == 0) wacc[tid >> 6] = make_float4(kc, cpo, lpo, 0.f);
    __syncthreads();
    kc  = wacc[0].x + wacc[1].x + wacc[2].x + wacc[3].x;
    cpo = wacc[0].y + wacc[1].y + wacc[2].y + wacc[3].y;
    lpo = wacc[0].z + wacc[1].z + wacc[2].z + wacc[3].z;
  }
  const float npn = kc;
  const int k = RATIO * (int)(kc + 0.5f);

  float hs = 0.0f;
  if (k >= PP) {
    float s = 0.0f;
#pragma unroll
    for (int i = 0; i < 9; ++i) {
      s += __uint_as_float(uv[i].x) + __uint_as_float(uv[i].y) +
           __uint_as_float(uv[i].z) + __uint_as_float(uv[i].w);
    }
#pragma unroll
    for (int d = 1; d < 64; d <<= 1) s += __shfl_xor(s, d);
    __syncthreads();
    if ((tid & 63) == 0) wredf[tid >> 6] = s;
    __syncthreads();
    hs = wredf[0] + wredf[1] + wredf[2] + wredf[3];
  } else if (k > 0) {
    unsigned lo = 0u, hi = 0x7f7fffffu;
    int it = 0;
    while (lo < hi) {
      unsigned span = hi - lo;
      unsigned q4 = span >> 2;
      unsigned m1, m2, m3;
      if (q4 == 0) { m1 = m2 = m3 = lo + ((span + 1) >> 1); }
      else { m1 = lo + q4; m2 = lo + 2 * q4; m3 = lo + 3 * q4; }
      int a1 = 0, a2 = 0, a3 = 0;
#pragma unroll
      for (int i = 0; i < 9; ++i) {
        a1 += (uv[i].x >= m1) + (uv[i].y >= m1) + (uv[i].z >= m1) + (uv[i].w >= m1);
        a2 += (uv[i].x >= m2) + (uv[i].y >= m2) + (uv[i].z >= m2) + (uv[i].w >= m2);
        a3 += (uv[i].x >= m3) + (uv[i].y >= m3) + (uv[i].z >= m3) + (uv[i].w >= m3);
      }
#pragma unroll
      for (int d = 1; d < 64; d <<= 1) {
        a1 += __shfl_xor(a1, d); a2 += __shfl_xor(a2, d); a3 += __shfl_xor(a3, d);
      }
      const int buf = it & 1;
      if ((tid & 63) == 0) cred[buf][tid >> 6] = make_int4(a1, a2, a3, 0);
      __syncthreads();
      int c1 = 0, c2 = 0, c3 = 0;
#pragma unroll
      for (int w = 0; w < 4; ++w) {
        int4 cc = cred[buf][w];
        c1 += cc.x; c2 += cc.y; c3 += cc.z;
      }
      if (c3 >= k) lo = m3;
      else if (c2 >= k) { lo = m2; hi = m3 - 1; }
      else if (c1 >= k) { lo = m1; hi = m2 - 1; }
      else hi = m1 - 1;
      ++it;
    }
    const float x = __uint_as_float(lo);
    float s = 0.0f; int c = 0;
#pragma unroll
    for (int i = 0; i < 9; ++i) {
      if (uv[i].x > lo) { s += __uint_as_float(uv[i].x); ++c; }
      if (uv[i].y > lo) { s += __uint_as_float(uv[i].y); ++c; }
      if (uv[i].z > lo) { s += __uint_as_float(uv[i].z); ++c; }
      if (uv[i].w > lo) { s += __uint_as_float(uv[i].w); ++c; }
    }
#pragma unroll
    for (int d = 1; d < 64; d <<= 1) { s += __shfl_xor(s, d); c += __shfl_xor(c, d); }
    __syncthreads();
    if ((tid & 63) == 0) { wredf[tid >> 6] = s; wcnt[tid >> 6] = c; }
    __syncthreads();
    hs = (wredf[0] + wredf[1] + wredf[2] + wredf[3]) +
         (float)(k - (wcnt[0] + wcnt[1] + wcnt[2] + wcnt[3])) * x;
  }

  if (tid == 0) {
    per_img[n] = make_float4(cpo, lpo, npn, hs);
    __threadfence();
    last_s = atomicAdd(counter, 1);
  }
  __syncthreads();
  if (last_s == NN - 1) {
    __threadfence();
    if (tid < 64) {
      float4 v = per_img[tid];
      float a = v.x, b = v.y, c = v.z, d = v.w;
#pragma unroll
      for (int dd = 1; dd < 64; dd <<= 1) {
        a += __shfl_xor(a, dd); b += __shfl_xor(b, dd);
        c += __shfl_xor(c, dd); d += __shfl_xor(d, dd);
      }
      if (tid == 0) out[0] = (a + d) / c + b / (c * 4.0f);
    }
  }
}

// ---------------------------------------------------------------------------
extern "C" void kernel_launch(void* const* d_in, const int* in_sizes, int n_in,
                              void* d_out, int out_size, void* d_ws, size_t ws_size,
                              hipStream_t stream) {
  const float*  pred_locs   = (const float*)d_in[0];
  const float*  pred_scores = (const float*)d_in[1];
  const float*  boxes       = (const float*)d_in[2];
  const int*    labels      = (const int*)d_in[3];
  const float*  priors      = (const float*)d_in[4];
  float* out = (float*)d_out;

  // workspace layout (16B-aligned sections)
  float4* partials = (float4*)d_ws;                               // TILES2
  float*  ce_neg = (float*)(partials + TILES2);                   // N*P
  u64* combined_part = (u64*)(ce_neg + (size_t)NN * PP);          // NN*BPI*MM
  u64* combined = combined_part + (size_t)NN * BPI * MM;          // NN*MM
  float4* per_img = (float4*)(combined + NN * MM);                // NN
  int* counter = (int*)(per_img + NN);                            // 1

  match_lite<<<NN * BPI, 256, 0, stream>>>((const float4*)boxes,
                                           (const float4*)priors,
                                           combined_part, counter);
  reduce_kernel<<<NN, 192, 0, stream>>>(combined_part, combined);
  ce_kernel<<<TILES2, BTHR, 0, stream>>>(pred_scores,
                                         (const float4*)pred_locs,
                                         (const float4*)priors,
                                         (const float4*)boxes, labels,
                                         combined, ce_neg, partials);
  hardneg_kernel<<<NN, 256, 0, stream>>>(ce_neg, partials, per_img,
                                         counter, out);
}

// Round 16
// 81.916 us; speedup vs baseline: 9.5303x; 1.0105x over previous
//
#include <hip/hip_runtime.h>

#define NN 64
#define PP 8732
#define CC 91
#define MM 20
#define RATIO 3
#define BPI 32                   // match blocks per image
#define CHUNK 273                // ceil(PP / BPI); last part gets 269
#define ROWS 128                 // ce rows per block
#define BTHR 512                 // ce threads per block
#define TILES2 ((NN * PP) / ROWS)   // 4366 ce tiles

typedef unsigned long long u64;
typedef unsigned short u16;

// ---------------------------------------------------------------------------
// Kernel A: matching (r12-proven best). 32 blocks/image x 256 threads;
// wave w owns objects [5w, 5w+5): per-object butterfly = 5 keys/thread;
// per-prior argmax combined across the 4 waves via LDS (exact cross-mul
// compares; wave order == ascending m; strict > keeps first-max tie-break).
// Emits packed u16 (obj<<8 | label-if-positive); per-object best prior in
// block-exclusive combined_part slices (no atomics, no zeroing).
// ---------------------------------------------------------------------------
__global__ __launch_bounds__(256) void match_b(
    const float4* __restrict__ boxes4,   // N*M (xyxy)
    const float4* __restrict__ priors4,  // P (cxcywh)
    const int* __restrict__ labels,      // N*M
    u16* __restrict__ minfo,             // N*P packed
    u64* __restrict__ combined_part,     // N*BPI*MM
    int* __restrict__ counter)           // [1] -> zeroed here
{
  __shared__ float pi_s[4][CHUNK];       // per-wave per-prior best inter
  __shared__ float pd_s[4][CHUNK];       // ... and denominator
  __shared__ short pm_s[4][CHUNK];       // ... and object (global m)
  __shared__ int lb[MM];
  const int blk = blockIdx.x, tid = threadIdx.x;
  const int wave = tid >> 6, lane = tid & 63;
  const int n = blk >> 5, part = blk & 31;
  const int c0 = part * CHUNK;
  const int cend = (c0 + CHUNK < PP) ? c0 + CHUNK : PP;
  const int clen = cend - c0;

  if (blockIdx.x == 0 && tid == 0) counter[0] = 0;
  if (tid < MM) lb[tid] = labels[n * MM + tid];

  // wave's 5 objects -> registers (uniform per wave)
  float obx0[5], oby0[5], obx1[5], oby1[5], oba[5];
#pragma unroll
  for (int j = 0; j < 5; ++j) {
    float4 b = boxes4[n * MM + wave * 5 + j];
    obx0[j] = b.x; oby0[j] = b.y; obx1[j] = b.z; oby1[j] = b.w;
    oba[j] = (b.z - b.x) * (b.w - b.y);
  }

  float bi[5], bd[5]; int bpp[5];
#pragma unroll
  for (int j = 0; j < 5; ++j) { bi[j] = 0.0f; bd[j] = 1.0f; bpp[j] = 0; }

  // phase 1: every wave scans the whole chunk against ITS 5 objects
#pragma unroll
  for (int i = 0; i < 5; ++i) {
    int pc = lane + (i << 6);
    if (pc < clen) {
      int p = c0 + pc;
      float4 pr = priors4[p];
      float hw = pr.z * 0.5f, hh = pr.w * 0.5f;
      float px0 = pr.x - hw, py0 = pr.y - hh, px1 = pr.x + hw, py1 = pr.y + hh;
      float pa = (px1 - px0) * (py1 - py0);   // ref rounding
      float pi = -1.0f, pd = 1.0f; int pm = 0;
#pragma unroll
      for (int j = 0; j < 5; ++j) {
        float iw = fminf(obx1[j], px1) - fmaxf(obx0[j], px0);
        float ih = fminf(oby1[j], py1) - fmaxf(oby0[j], py0);
        iw = fmaxf(iw, 0.0f); ih = fmaxf(ih, 0.0f);
        float inter = iw * ih;
        float den = (oba[j] + pa) - inter;
        bool cA = inter * pd > pi * den;          // first j wins ties
        pi = cA ? inter : pi; pd = cA ? den : pd;
        pm = cA ? (wave * 5 + j) : pm;
        bool cB = inter * bd[j] > bi[j] * den;    // lowest p wins ties
        bi[j] = cB ? inter : bi[j]; bd[j] = cB ? den : bd[j];
        bpp[j] = cB ? p : bpp[j];
      }
      pi_s[wave][pc] = pi; pd_s[wave][pc] = pd; pm_s[wave][pc] = (short)pm;
    }
  }

  // phase 2: per-object butterfly over the wave (5 keys), one division each
#pragma unroll
  for (int j = 0; j < 5; ++j) {
    float r = bi[j] / bd[j];                   // IEEE quotient, >=0
    u64 key = ((u64)__float_as_uint(r) << 32) | (unsigned)(~(unsigned)bpp[j]);
#pragma unroll
    for (int d = 1; d < 64; d <<= 1) {
      u64 o = __shfl_xor(key, d);
      key = (o > key) ? o : key;
    }
    if (lane == 0) combined_part[blk * MM + wave * 5 + j] = key;
  }
  __syncthreads();

  // phase 3: combine 4 waves per prior (ascending m, strict >) + emit minfo
  for (int pc = tid; pc < clen; pc += 256) {
    float pi = pi_s[0][pc], pd = pd_s[0][pc]; int pm = pm_s[0][pc];
#pragma unroll
    for (int w = 1; w < 4; ++w) {
      float qi = pi_s[w][pc], qd = pd_s[w][pc];
      bool c = qi * pd > pi * qd;               // later m only if strictly >
      int qm = pm_s[w][pc];
      pi = c ? qi : pi; pd = c ? qd : pd; pm = c ? qm : pm;
    }
    float q = pi / pd;                          // IEEE quotient (ref)
    int lab8 = (q < 0.5f) ? 0 : lb[pm];         // labels 1..90, never 0
    minfo[(size_t)n * PP + c0 + pc] = (u16)((pm << 8) | lab8);
  }
}

// ---------------------------------------------------------------------------
// Kernel B: CE + matching emit + smooth-L1 loc loss (r8-proven direct-global
// score path). 128 rows/block, 512 threads; table-stage folds BPI=32 parts.
// partials[b] = (conf_pos_sum, loc_sum, n_pos img n0, n_pos img n0+1).
// ---------------------------------------------------------------------------
__global__ __launch_bounds__(BTHR) void ce_kernel(
    const float* __restrict__ scores,        // N*P*C
    const float4* __restrict__ pred_locs4,   // N*P
    const float4* __restrict__ priors4,      // P
    const float4* __restrict__ boxes4,       // N*M
    const int* __restrict__ labels,          // N*M
    const u16* __restrict__ minfo,           // N*P
    const u64* __restrict__ combined_part,   // N*BPI*MM
    float* __restrict__ ce_neg,              // N*P (0 where positive)
    float4* __restrict__ partials)           // [TILES2]
{
  __shared__ unsigned key_lo[2][MM];
  __shared__ int lbl_s[2][MM];
  __shared__ float4 box_s[2][MM];
  __shared__ float4 w8[8];
  const int tid = threadIdx.x;
  const long base = (long)blockIdx.x * ROWS;
  const int n0 = (int)(base / PP);
  const int rem0 = (int)(base - (long)n0 * PP);
  const int r = tid >> 2, l = tid & 3;
  const long row = base + r;

  const int mi = minfo[row];   // broadcast per row

  if (tid < MM) {
    const u64* cp = combined_part + (size_t)n0 * BPI * MM;
    u64 best = cp[tid];
#pragma unroll
    for (int w = 1; w < BPI; ++w) { u64 o = cp[w * MM + tid]; best = (o > best) ? o : best; }
    key_lo[0][tid] = (unsigned)best;
    lbl_s[0][tid]  = labels[n0 * MM + tid];
    box_s[0][tid]  = boxes4[n0 * MM + tid];
  } else if (tid >= 64 && tid < 64 + MM) {
    int j = tid - 64, nn = (n0 + 1 < NN) ? n0 + 1 : NN - 1;
    const u64* cp = combined_part + (size_t)nn * BPI * MM;
    u64 best = cp[j];
#pragma unroll
    for (int w = 1; w < BPI; ++w) { u64 o = cp[w * MM + j]; best = (o > best) ? o : best; }
    key_lo[1][j] = (unsigned)best;
    lbl_s[1][j]  = labels[nn * MM + j];
    box_s[1][j]  = boxes4[nn * MM + j];
  }

  const float* rp = scores + (size_t)row * CC;
  float ss0 = 0.f, ss1 = 0.f, ss2 = 0.f, ss3 = 0.f;
#pragma unroll
  for (int j = 0; j < 23; ++j) {
    int c = l + 4 * j;
    if (c < CC) {
      float e = __expf(rp[c]);
      if ((j & 3) == 0) ss0 += e;
      else if ((j & 3) == 1) ss1 += e;
      else if ((j & 3) == 2) ss2 += e;
      else ss3 += e;
    }
  }
  float s = (ss0 + ss1) + (ss2 + ss3);
  s += __shfl_xor(s, 1);
  s += __shfl_xor(s, 2);

  __syncthreads();   // tables ready

  float cp_ = 0.0f, lp_ = 0.0f; int pos0 = 0, pos1 = 0;
  if (l == 0) {
    const int bn = (rem0 + r >= PP) ? 1 : 0;
    const int p = rem0 + r - bn * PP;
    int mm_ = -1;
    const unsigned want = ~(unsigned)p;
#pragma unroll
    for (int j = 0; j < MM; ++j) if (key_lo[bn][j] == want) mm_ = j;   // last wins
    bool pos; int lab, sm;
    if (mm_ >= 0) { pos = true; sm = mm_; lab = lbl_s[bn][mm_]; }
    else { lab = mi & 0xff; pos = (lab != 0); sm = mi >> 8; }
    float ce = __logf(s) - rp[lab];
    if (pos) {
      cp_ = ce; ce_neg[row] = 0.0f;
      if (bn) pos1 = 1; else pos0 = 1;
      float4 bx = box_s[bn][sm], pr = priors4[p], pl = pred_locs4[row];
      float cx = (bx.x + bx.z) * 0.5f, cy = (bx.y + bx.w) * 0.5f;
      float w = bx.z - bx.x, h = bx.w - bx.y;
      float gx = (cx - pr.x) / (pr.z / 10.0f);
      float gy = (cy - pr.y) / (pr.w / 10.0f);
      float gz = __logf(w / pr.z) * 5.0f;
      float gw = __logf(h / pr.w) * 5.0f;
      float d, a;
      d = pl.x - gx; a = fabsf(d); lp_ += (a < 1.0f) ? 0.5f * d * d : a - 0.5f;
      d = pl.y - gy; a = fabsf(d); lp_ += (a < 1.0f) ? 0.5f * d * d : a - 0.5f;
      d = pl.z - gz; a = fabsf(d); lp_ += (a < 1.0f) ? 0.5f * d * d : a - 0.5f;
      d = pl.w - gw; a = fabsf(d); lp_ += (a < 1.0f) ? 0.5f * d * d : a - 0.5f;
    } else {
      ce_neg[row] = fmaxf(ce, 0.0f);   // >=0 keeps uint order == float order
    }
  }

#pragma unroll
  for (int d = 1; d < 64; d <<= 1) {
    cp_ += __shfl_xor(cp_, d); lp_ += __shfl_xor(lp_, d);
    pos0 += __shfl_xor(pos0, d); pos1 += __shfl_xor(pos1, d);
  }
  if ((tid & 63) == 0)
    w8[tid >> 6] = make_float4(cp_, lp_, (float)pos0, (float)pos1);
  __syncthreads();
  if (tid == 0) {
    float sx = 0.f, sy = 0.f, sz = 0.f, sw = 0.f;
#pragma unroll
    for (int w = 0; w < 8; ++w) { sx += w8[w].x; sy += w8[w].y; sz += w8[w].z; sw += w8[w].w; }
    partials[blockIdx.x] = make_float4(sx, sy, sz, sw);
  }
}

// ---------------------------------------------------------------------------
// Kernel C: hard-negative mining (4-ary bisection, uint4 loads) + fused final.
// ---------------------------------------------------------------------------
__global__ __launch_bounds__(256) void hardneg_kernel(
    const float* __restrict__ ce_neg, const float4* __restrict__ partials,
    float4* __restrict__ per_img, int* __restrict__ counter,
    float* __restrict__ out)
{
  __shared__ int4 cred[2][4];
  __shared__ float wredf[4];
  __shared__ int wcnt[4];
  __shared__ float4 wacc[4];
  __shared__ int last_s;
  const int n = blockIdx.x, tid = threadIdx.x;

  // PP = 8732 = 4*2183 exactly: image slice is uint4-aligned and exact
  uint4 uv[9];
  {
    const uint4* cn4 = (const uint4*)(ce_neg + (size_t)n * PP);
#pragma unroll
    for (int i = 0; i < 9; ++i) {
      int f = tid + (i << 8);
      uv[i] = (f < 2183) ? cn4[f] : make_uint4(0u, 0u, 0u, 0u);
    }
  }

  float kc = 0.0f, cpo = 0.0f, lpo = 0.0f;
  {
    const int bstart = (n * PP) / ROWS;
    const int bend = ((n + 1) * PP - 1) / ROWS;
    const int ost = (n * PP + ROWS - 1) / ROWS;
    const int oen = ((n + 1) * PP + ROWS - 1) / ROWS;
    for (int b = bstart + tid; b <= bend; b += 256) {
      float4 pb = partials[b];
      int nb0 = (b * ROWS) / PP;
      if (nb0 == n)     kc += pb.z;
      if (nb0 + 1 == n) kc += pb.w;
      if (b >= ost && b < oen) { cpo += pb.x; lpo += pb.y; }
    }
#pragma unroll
    for (int d = 1; d < 64; d <<= 1) {
      kc += __shfl_xor(kc, d); cpo += __shfl_xor(cpo, d);
      lpo += __shfl_xor(lpo, d);
    }
    if ((tid & 63) == 0) wacc[tid >> 6] = make_float4(kc, cpo, lpo, 0.f);
    __syncthreads();
    kc  = wacc[0].x + wacc[1].x + wacc[2].x + wacc[3].x;
    cpo = wacc[0].y + wacc[1].y + wacc[2].y + wacc[3].y;
    lpo = wacc[0].z + wacc[1].z + wacc[2].z + wacc[3].z;
  }
  const float npn = kc;
  const int k = RATIO * (int)(kc + 0.5f);

  float hs = 0.0f;
  if (k >= PP) {
    float s = 0.0f;
#pragma unroll
    for (int i = 0; i < 9; ++i) {
      s += __uint_as_float(uv[i].x) + __uint_as_float(uv[i].y) +
           __uint_as_float(uv[i].z) + __uint_as_float(uv[i].w);
    }
#pragma unroll
    for (int d = 1; d < 64; d <<= 1) s += __shfl_xor(s, d);
    __syncthreads();
    if ((tid & 63) == 0) wredf[tid >> 6] = s;
    __syncthreads();
    hs = wredf[0] + wredf[1] + wredf[2] + wredf[3];
  } else if (k > 0) {
    unsigned lo = 0u, hi = 0x7f7fffffu;
    int it = 0;
    while (lo < hi) {
      unsigned span = hi - lo;
      unsigned q4 = span >> 2;
      unsigned m1, m2, m3;
      if (q4 == 0) { m1 = m2 = m3 = lo + ((span + 1) >> 1); }
      else { m1 = lo + q4; m2 = lo + 2 * q4; m3 = lo + 3 * q4; }
      int a1 = 0, a2 = 0, a3 = 0;
#pragma unroll
      for (int i = 0; i < 9; ++i) {
        a1 += (uv[i].x >= m1) + (uv[i].y >= m1) + (uv[i].z >= m1) + (uv[i].w >= m1);
        a2 += (uv[i].x >= m2) + (uv[i].y >= m2) + (uv[i].z >= m2) + (uv[i].w >= m2);
        a3 += (uv[i].x >= m3) + (uv[i].y >= m3) + (uv[i].z >= m3) + (uv[i].w >= m3);
      }
#pragma unroll
      for (int d = 1; d < 64; d <<= 1) {
        a1 += __shfl_xor(a1, d); a2 += __shfl_xor(a2, d); a3 += __shfl_xor(a3, d);
      }
      const int buf = it & 1;
      if ((tid & 63) == 0) cred[buf][tid >> 6] = make_int4(a1, a2, a3, 0);
      __syncthreads();
      int c1 = 0, c2 = 0, c3 = 0;
#pragma unroll
      for (int w = 0; w < 4; ++w) {
        int4 cc = cred[buf][w];
        c1 += cc.x; c2 += cc.y; c3 += cc.z;
      }
      if (c3 >= k) lo = m3;
      else if (c2 >= k) { lo = m2; hi = m3 - 1; }
      else if (c1 >= k) { lo = m1; hi = m2 - 1; }
      else hi = m1 - 1;
      ++it;
    }
    const float x = __uint_as_float(lo);
    float s = 0.0f; int c = 0;
#pragma unroll
    for (int i = 0; i < 9; ++i) {
      if (uv[i].x > lo) { s += __uint_as_float(uv[i].x); ++c; }
      if (uv[i].y > lo) { s += __uint_as_float(uv[i].y); ++c; }
      if (uv[i].z > lo) { s += __uint_as_float(uv[i].z); ++c; }
      if (uv[i].w > lo) { s += __uint_as_float(uv[i].w); ++c; }
    }
#pragma unroll
    for (int d = 1; d < 64; d <<= 1) { s += __shfl_xor(s, d); c += __shfl_xor(c, d); }
    __syncthreads();
    if ((tid & 63) == 0) { wredf[tid >> 6] = s; wcnt[tid >> 6] = c; }
    __syncthreads();
    hs = (wredf[0] + wredf[1] + wredf[2] + wredf[3]) +
         (float)(k - (wcnt[0] + wcnt[1] + wcnt[2] + wcnt[3])) * x;
  }

  if (tid == 0) {
    per_img[n] = make_float4(cpo, lpo, npn, hs);
    __threadfence();
    last_s = atomicAdd(counter, 1);
  }
  __syncthreads();
  if (last_s == NN - 1) {
    __threadfence();
    if (tid < 64) {
      float4 v = per_img[tid];
      float a = v.x, b = v.y, c = v.z, d = v.w;
#pragma unroll
      for (int dd = 1; dd < 64; dd <<= 1) {
        a += __shfl_xor(a, dd); b += __shfl_xor(b, dd);
        c += __shfl_xor(c, dd); d += __shfl_xor(d, dd);
      }
      if (tid == 0) out[0] = (a + d) / c + b / (c * 4.0f);
    }
  }
}

// ---------------------------------------------------------------------------
extern "C" void kernel_launch(void* const* d_in, const int* in_sizes, int n_in,
                              void* d_out, int out_size, void* d_ws, size_t ws_size,
                              hipStream_t stream) {
  const float*  pred_locs   = (const float*)d_in[0];
  const float*  pred_scores = (const float*)d_in[1];
  const float*  boxes       = (const float*)d_in[2];
  const int*    labels      = (const int*)d_in[3];
  const float*  priors      = (const float*)d_in[4];
  float* out = (float*)d_out;

  u16* minfo = (u16*)d_ws;                                        // N*P u16
  float4* partials = (float4*)(minfo + (size_t)NN * PP);          // TILES2
  float*  ce_neg = (float*)(partials + TILES2);                   // N*P
  u64* combined_part = (u64*)(ce_neg + (size_t)NN * PP);          // N*BPI*MM
  float4* per_img = (float4*)(combined_part + (size_t)NN * BPI * MM); // NN
  int* counter = (int*)(per_img + NN);                            // 1

  match_b<<<NN * BPI, 256, 0, stream>>>((const float4*)boxes,
                                        (const float4*)priors, labels,
                                        minfo, combined_part, counter);
  ce_kernel<<<TILES2, BTHR, 0, stream>>>(pred_scores,
                                         (const float4*)pred_locs,
                                         (const float4*)priors,
                                         (const float4*)boxes, labels,
                                         minfo, combined_part,
                                         ce_neg, partials);
  hardneg_kernel<<<NN, 256, 0, stream>>>(ce_neg, partials, per_img,
                                         counter, out);
}